// Round 1
// baseline (271.431 us; speedup 1.0000x reference)
//
#include <hip/hip_runtime.h>
#include <hip/hip_bf16.h>

// Problem constants
constexpr int BATCH = 4;
constexpr int SEQ   = 4096;
constexpr int DIM   = 128;   // head size

typedef __bf16 bf16x8 __attribute__((ext_vector_type(8)));
typedef float  f32x4  __attribute__((ext_vector_type(4)));

// ---------------------------------------------------------------------------
// Kernel 1: QKV projection.  q/k/v = x @ W{q,k,v}, output bf16 into workspace.
// Block: 256 threads (4 waves), handles 128 rows of x. Grid: B*T/128 = 128.
// ---------------------------------------------------------------------------
__global__ __launch_bounds__(256) void qkv_proj(
    const float* __restrict__ x,
    const float* __restrict__ Wq, const float* __restrict__ Wk,
    const float* __restrict__ Wv,
    __bf16* __restrict__ q, __bf16* __restrict__ k, __bf16* __restrict__ v)
{
    __shared__ __bf16 Xl[128][136];   // x tile, bf16, padded stride
    __shared__ __bf16 Wt[128][136];   // W transposed: Wt[d][c]

    const int t    = threadIdx.x;
    const int lane = t & 63;
    const int w    = t >> 6;
    const int l15  = lane & 15;
    const int l4   = lane >> 4;
    const int rowblk = blockIdx.x * 128;

    // Load X tile (128x128 f32) -> bf16 LDS. 4096 float4 / 256 thr = 16 each.
    #pragma unroll
    for (int i = 0; i < 16; ++i) {
        int idx = i * 256 + t;
        int r   = idx >> 5;
        int c4  = (idx & 31) << 2;
        float4 f = *(const float4*)(x + (size_t)(rowblk + r) * DIM + c4);
        __bf16* dst = &Xl[r][c4];
        dst[0] = (__bf16)f.x; dst[1] = (__bf16)f.y;
        dst[2] = (__bf16)f.z; dst[3] = (__bf16)f.w;
    }

    const float* Ws[3]  = {Wq, Wk, Wv};
    __bf16*      Os[3]  = {q, k, v};

    #pragma unroll
    for (int m = 0; m < 3; ++m) {
        __syncthreads();   // prev compute done (also covers X-load on m=0 path below)
        const float* W = Ws[m];
        // load W (row-major [c][d]) transposed into Wt[d][c]
        #pragma unroll
        for (int i = 0; i < 16; ++i) {
            int idx = i * 256 + t;
            int r   = idx >> 5;          // c
            int c4  = (idx & 31) << 2;   // d base
            float4 f = *(const float4*)(W + (size_t)r * DIM + c4);
            Wt[c4 + 0][r] = (__bf16)f.x;
            Wt[c4 + 1][r] = (__bf16)f.y;
            Wt[c4 + 2][r] = (__bf16)f.z;
            Wt[c4 + 3][r] = (__bf16)f.w;
        }
        __syncthreads();

        // wave w computes rows [w*32, w*32+32)
        f32x4 acc[2][8];
        #pragma unroll
        for (int a = 0; a < 2; ++a)
            #pragma unroll
            for (int cf = 0; cf < 8; ++cf) acc[a][cf] = (f32x4){0.f, 0.f, 0.f, 0.f};

        #pragma unroll
        for (int kc = 0; kc < 4; ++kc) {
            bf16x8 af0 = *(const bf16x8*)&Xl[w * 32 +      l15][kc * 32 + l4 * 8];
            bf16x8 af1 = *(const bf16x8*)&Xl[w * 32 + 16 + l15][kc * 32 + l4 * 8];
            #pragma unroll
            for (int cf = 0; cf < 8; ++cf) {
                bf16x8 bfr = *(const bf16x8*)&Wt[cf * 16 + l15][kc * 32 + l4 * 8];
                acc[0][cf] = __builtin_amdgcn_mfma_f32_16x16x32_bf16(af0, bfr, acc[0][cf], 0, 0, 0);
                acc[1][cf] = __builtin_amdgcn_mfma_f32_16x16x32_bf16(af1, bfr, acc[1][cf], 0, 0, 0);
            }
        }

        __bf16* op = Os[m];
        #pragma unroll
        for (int a = 0; a < 2; ++a)
            #pragma unroll
            for (int cf = 0; cf < 8; ++cf)
                #pragma unroll
                for (int r2 = 0; r2 < 4; ++r2) {
                    int row = rowblk + w * 32 + a * 16 + l4 * 4 + r2;
                    int col = cf * 16 + l15;
                    op[(size_t)row * DIM + col] = (__bf16)acc[a][cf][r2];
                }
    }
}

// ---------------------------------------------------------------------------
// Kernel 2: causal flash attention over bf16 q/k/v, f32 output.
// Grid: (T/64, B). Block: 256 threads = 4 waves, each wave owns 16 Q rows.
// K tile [64][136] LDS; V transposed into Vt[128][72] with 8-key-chunk XOR
// swizzle; P through per-wave LDS to reach A-fragment layout.
// ---------------------------------------------------------------------------
__global__ __launch_bounds__(256) void attn(
    const __bf16* __restrict__ q, const __bf16* __restrict__ k,
    const __bf16* __restrict__ v, float* __restrict__ out)
{
    __shared__ __bf16 Kl[64][136];
    __shared__ __bf16 Vt[128][72];
    __shared__ __bf16 Pl[4][16][72];

    const int t    = threadIdx.x;
    const int lane = t & 63;
    const int w    = t >> 6;
    const int l15  = lane & 15;
    const int l4   = lane >> 4;
    const int b    = blockIdx.y;
    const int qt   = blockIdx.x;
    const int qb0  = qt * 64;
    const size_t base = (size_t)b * SEQ * DIM;

    // Q fragments (A-operand layout: row = l15, k = l4*8 + j + 32*dc)
    bf16x8 qf[4];
    {
        const __bf16* qrow = q + base + (size_t)(qb0 + w * 16 + l15) * DIM;
        #pragma unroll
        for (int dc = 0; dc < 4; ++dc)
            qf[dc] = *(const bf16x8*)(qrow + dc * 32 + l4 * 8);
    }

    f32x4 o[8];
    #pragma unroll
    for (int i = 0; i < 8; ++i) o[i] = (f32x4){0.f, 0.f, 0.f, 0.f};
    float mr[4], lr[4];
    #pragma unroll
    for (int r = 0; r < 4; ++r) { mr[r] = -INFINITY; lr[r] = 0.f; }

    const float scale = 0.08838834764831845f;  // 1/sqrt(128)

    for (int jt = 0; jt <= qt; ++jt) {
        __syncthreads();   // all waves done reading Kl/Vt of previous tile

        // ---- load K (linear, padded) and V (transposed + chunk-swizzled) ----
        {
            const __bf16* kg = k + base + (size_t)jt * 64 * DIM;
            const __bf16* vg = v + base + (size_t)jt * 64 * DIM;
            int rr = t >> 4;             // 0..15
            int c  = (t & 15) * 8;       // d base, 0..120
            #pragma unroll
            for (int i = 0; i < 4; ++i) {
                int row = i * 16 + rr;   // key index 0..63
                *(int4*)&Kl[row][c] = *(const int4*)(kg + (size_t)row * DIM + c);
                bf16x8 vv = *(const bf16x8*)(vg + (size_t)row * DIM + c);
                #pragma unroll
                for (int j = 0; j < 8; ++j) {
                    int cc  = c + j;  // d index
                    int col = (((row >> 3) ^ ((cc >> 3) & 7)) << 3) | (row & 7);
                    Vt[cc][col] = vv[j];
                }
            }
        }
        __syncthreads();

        // ---- S = Q K^T (16x64 per wave) ----
        f32x4 s[4];
        #pragma unroll
        for (int kc = 0; kc < 4; ++kc) {
            f32x4 acc = (f32x4){0.f, 0.f, 0.f, 0.f};
            #pragma unroll
            for (int dc = 0; dc < 4; ++dc) {
                bf16x8 kf = *(const bf16x8*)&Kl[kc * 16 + l15][dc * 32 + l4 * 8];
                acc = __builtin_amdgcn_mfma_f32_16x16x32_bf16(qf[dc], kf, acc, 0, 0, 0);
            }
            s[kc] = acc;
        }

        // ---- scale + causal mask + online softmax ----
        const bool diag = (jt == qt);
        float rowmax[4];
        #pragma unroll
        for (int r = 0; r < 4; ++r) rowmax[r] = -INFINITY;
        #pragma unroll
        for (int kc = 0; kc < 4; ++kc) {
            int key = jt * 64 + kc * 16 + l15;
            #pragma unroll
            for (int r = 0; r < 4; ++r) {
                float sv = s[kc][r] * scale;
                if (diag) {
                    int qrow = qb0 + w * 16 + l4 * 4 + r;
                    if (key > qrow) sv = -INFINITY;
                }
                s[kc][r] = sv;
                rowmax[r] = fmaxf(rowmax[r], sv);
            }
        }
        #pragma unroll
        for (int r = 0; r < 4; ++r) {
            float x2 = rowmax[r];
            x2 = fmaxf(x2, __shfl_xor(x2, 1));
            x2 = fmaxf(x2, __shfl_xor(x2, 2));
            x2 = fmaxf(x2, __shfl_xor(x2, 4));
            x2 = fmaxf(x2, __shfl_xor(x2, 8));
            rowmax[r] = x2;
        }
        float alpha[4];
        #pragma unroll
        for (int r = 0; r < 4; ++r) {
            float mnew = fmaxf(mr[r], rowmax[r]);
            alpha[r]   = __expf(mr[r] - mnew);
            mr[r]      = mnew;
        }
        float rowsum[4] = {0.f, 0.f, 0.f, 0.f};
        #pragma unroll
        for (int kc = 0; kc < 4; ++kc)
            #pragma unroll
            for (int r = 0; r < 4; ++r) {
                float p = __expf(s[kc][r] - mr[r]);   // -inf -> 0
                s[kc][r] = p;
                rowsum[r] += p;
            }
        #pragma unroll
        for (int r = 0; r < 4; ++r) {
            float x2 = rowsum[r];
            x2 += __shfl_xor(x2, 1);
            x2 += __shfl_xor(x2, 2);
            x2 += __shfl_xor(x2, 4);
            x2 += __shfl_xor(x2, 8);
            lr[r] = lr[r] * alpha[r] + x2;
        }
        // rescale O
        #pragma unroll
        for (int df = 0; df < 8; ++df)
            #pragma unroll
            for (int r = 0; r < 4; ++r) o[df][r] *= alpha[r];

        // ---- P -> bf16 A-fragment layout via per-wave LDS ----
        #pragma unroll
        for (int kc = 0; kc < 4; ++kc)
            #pragma unroll
            for (int r = 0; r < 4; ++r)
                Pl[w][l4 * 4 + r][kc * 16 + l15] = (__bf16)s[kc][r];
        // same-wave RAW on LDS: in-order DS FIFO + compiler lgkmcnt

        // ---- O += P V ----
        #pragma unroll
        for (int pc = 0; pc < 2; ++pc) {
            bf16x8 pa = *(const bf16x8*)&Pl[w][l15][pc * 32 + l4 * 8];
            #pragma unroll
            for (int df = 0; df < 8; ++df) {
                int cc  = df * 16 + l15;                       // d index
                int kch = (pc * 4 + l4) ^ ((cc >> 3) & 7);     // unswizzle
                bf16x8 vf = *(const bf16x8*)&Vt[cc][kch * 8];
                o[df] = __builtin_amdgcn_mfma_f32_16x16x32_bf16(pa, vf, o[df], 0, 0, 0);
            }
        }
    }

    // ---- epilogue: O / l -> f32 out ----
    float inv[4];
    #pragma unroll
    for (int r = 0; r < 4; ++r) inv[r] = 1.0f / lr[r];
    float* op = out + base;
    #pragma unroll
    for (int df = 0; df < 8; ++df)
        #pragma unroll
        for (int r = 0; r < 4; ++r) {
            int row = qb0 + w * 16 + l4 * 4 + r;
            op[(size_t)row * DIM + df * 16 + l15] = o[df][r] * inv[r];
        }
}

// ---------------------------------------------------------------------------
extern "C" void kernel_launch(void* const* d_in, const int* in_sizes, int n_in,
                              void* d_out, int out_size, void* d_ws, size_t ws_size,
                              hipStream_t stream) {
    const float* x  = (const float*)d_in[0];
    const float* Wq = (const float*)d_in[1];
    const float* Wk = (const float*)d_in[2];
    const float* Wv = (const float*)d_in[3];
    float* out = (float*)d_out;

    __bf16* qw = (__bf16*)d_ws;
    __bf16* kw = qw + (size_t)BATCH * SEQ * DIM;
    __bf16* vw = kw + (size_t)BATCH * SEQ * DIM;

    qkv_proj<<<dim3(BATCH * SEQ / 128), 256, 0, stream>>>(x, Wq, Wk, Wv, qw, kw, vw);
    attn<<<dim3(SEQ / 64, BATCH), 256, 0, stream>>>(qw, kw, vw, out);
}

// Round 2
// 107.235 us; speedup vs baseline: 2.5312x; 2.5312x over previous
//
#include <hip/hip_runtime.h>
#include <hip/hip_bf16.h>

// Problem constants
constexpr int BATCH = 4;
constexpr int SEQ   = 4096;
constexpr int DIM   = 128;   // head size

// Split-KV config: KV tiles are 64 keys; CHUNK tiles per split block.
constexpr int CHUNK       = 8;                    // 512 keys per block
constexpr int TASKS_PER_B = 288;                  // sum_qt ceil((qt+1)/8)
constexpr int SLOT_F32    = 64 + 64 + 64 * 128;   // m[64], l[64], O[64][128]
constexpr size_t QKV_BYTES  = (size_t)3 * BATCH * SEQ * DIM * 2;
constexpr size_t PART_BYTES = (size_t)BATCH * TASKS_PER_B * SLOT_F32 * 4;

typedef __bf16 bf16x8 __attribute__((ext_vector_type(8)));
typedef float  f32x4  __attribute__((ext_vector_type(4)));

// ---------------------------------------------------------------------------
// Kernel 1: QKV projection. Grid (128, 3): blockIdx.y picks q/k/v so all
// 256 CUs get work (was 128 blocks). 256 thr = 4 waves, 128 rows of x each.
// ---------------------------------------------------------------------------
__global__ __launch_bounds__(256) void qkv_proj(
    const float* __restrict__ x,
    const float* __restrict__ Wq, const float* __restrict__ Wk,
    const float* __restrict__ Wv,
    __bf16* __restrict__ q, __bf16* __restrict__ k, __bf16* __restrict__ v)
{
    __shared__ __bf16 Xl[128][136];
    __shared__ __bf16 Wt[128][136];   // W transposed: Wt[d][c]

    const int t    = threadIdx.x;
    const int lane = t & 63;
    const int w    = t >> 6;
    const int l15  = lane & 15;
    const int l4   = lane >> 4;
    const int rowblk = blockIdx.x * 128;
    const int m      = blockIdx.y;

    const float* W  = (m == 0) ? Wq : (m == 1) ? Wk : Wv;
    __bf16*      op = (m == 0) ? q  : (m == 1) ? k  : v;

    // X tile (128x128 f32) -> bf16 LDS
    #pragma unroll
    for (int i = 0; i < 16; ++i) {
        int idx = i * 256 + t;
        int r   = idx >> 5;
        int c4  = (idx & 31) << 2;
        float4 f = *(const float4*)(x + (size_t)(rowblk + r) * DIM + c4);
        __bf16* dst = &Xl[r][c4];
        dst[0] = (__bf16)f.x; dst[1] = (__bf16)f.y;
        dst[2] = (__bf16)f.z; dst[3] = (__bf16)f.w;
    }
    // W (row-major [c][d]) transposed into Wt[d][c]
    #pragma unroll
    for (int i = 0; i < 16; ++i) {
        int idx = i * 256 + t;
        int r   = idx >> 5;
        int c4  = (idx & 31) << 2;
        float4 f = *(const float4*)(W + (size_t)r * DIM + c4);
        Wt[c4 + 0][r] = (__bf16)f.x;
        Wt[c4 + 1][r] = (__bf16)f.y;
        Wt[c4 + 2][r] = (__bf16)f.z;
        Wt[c4 + 3][r] = (__bf16)f.w;
    }
    __syncthreads();

    f32x4 acc[2][8];
    #pragma unroll
    for (int a = 0; a < 2; ++a)
        #pragma unroll
        for (int cf = 0; cf < 8; ++cf) acc[a][cf] = (f32x4){0.f, 0.f, 0.f, 0.f};

    #pragma unroll
    for (int kc = 0; kc < 4; ++kc) {
        bf16x8 af0 = *(const bf16x8*)&Xl[w * 32 +      l15][kc * 32 + l4 * 8];
        bf16x8 af1 = *(const bf16x8*)&Xl[w * 32 + 16 + l15][kc * 32 + l4 * 8];
        #pragma unroll
        for (int cf = 0; cf < 8; ++cf) {
            bf16x8 bfr = *(const bf16x8*)&Wt[cf * 16 + l15][kc * 32 + l4 * 8];
            acc[0][cf] = __builtin_amdgcn_mfma_f32_16x16x32_bf16(af0, bfr, acc[0][cf], 0, 0, 0);
            acc[1][cf] = __builtin_amdgcn_mfma_f32_16x16x32_bf16(af1, bfr, acc[1][cf], 0, 0, 0);
        }
    }

    #pragma unroll
    for (int a = 0; a < 2; ++a)
        #pragma unroll
        for (int cf = 0; cf < 8; ++cf)
            #pragma unroll
            for (int r2 = 0; r2 < 4; ++r2) {
                int row = rowblk + w * 32 + a * 16 + l4 * 4 + r2;
                int col = cf * 16 + l15;
                op[(size_t)row * DIM + col] = (__bf16)acc[a][cf][r2];
            }
}

// ---------------------------------------------------------------------------
// Kernel 2: causal flash attention, split-KV.
// SPLIT=true : grid (288, B); block = (b, qt, chunk) via triangular decode,
//              processes KV tiles [chunk*8, min(chunk*8+8, qt+1)).
//              nch==1 -> direct write; else partial (m,l,O) to workspace.
// SPLIT=false: grid (64, B); block = full row of KV tiles (fallback).
// ---------------------------------------------------------------------------
template <bool SPLIT>
__global__ __launch_bounds__(256) void attn(
    const __bf16* __restrict__ q, const __bf16* __restrict__ k,
    const __bf16* __restrict__ v, float* __restrict__ out,
    float* __restrict__ part)
{
    __shared__ __bf16 Kl[64][136];
    __shared__ __bf16 Vt[128][72];
    __shared__ __bf16 Pl[4][16][72];

    const int t    = threadIdx.x;
    const int lane = t & 63;
    const int w    = t >> 6;
    const int l15  = lane & 15;
    const int l4   = lane >> 4;
    const int b    = blockIdx.y;

    int qt, chunk, nch, slot = 0;
    if (SPLIT) {
        int j = blockIdx.x;                 // 0..287
        int g = 0;
        while (g < 7 && j >= 4 * (g + 1) * (g + 2)) ++g;
        int r = j - 4 * g * (g + 1);
        nch   = g + 1;
        qt    = 8 * g + r / nch;
        chunk = r - (r / nch) * nch;
        slot  = b * TASKS_PER_B + j;
    } else {
        qt = blockIdx.x; chunk = 0; nch = 1;
    }
    const int qb0 = qt * 64;
    const int jt0 = chunk * CHUNK;
    const int jtE = SPLIT ? min(jt0 + CHUNK, qt + 1) : qt + 1;
    const size_t base = (size_t)b * SEQ * DIM;

    // Q fragments (A-operand layout: row = l15, k = l4*8 + j + 32*dc)
    bf16x8 qf[4];
    {
        const __bf16* qrow = q + base + (size_t)(qb0 + w * 16 + l15) * DIM;
        #pragma unroll
        for (int dc = 0; dc < 4; ++dc)
            qf[dc] = *(const bf16x8*)(qrow + dc * 32 + l4 * 8);
    }

    f32x4 o[8];
    #pragma unroll
    for (int i = 0; i < 8; ++i) o[i] = (f32x4){0.f, 0.f, 0.f, 0.f};
    float mr[4], lr[4];
    #pragma unroll
    for (int r = 0; r < 4; ++r) { mr[r] = -INFINITY; lr[r] = 0.f; }

    const float scale = 0.08838834764831845f;  // 1/sqrt(128)

    for (int jt = jt0; jt < jtE; ++jt) {
        __syncthreads();

        // ---- load K (linear, padded) and V (transposed + chunk-swizzled) ----
        {
            const __bf16* kg = k + base + (size_t)jt * 64 * DIM;
            const __bf16* vg = v + base + (size_t)jt * 64 * DIM;
            int rr = t >> 4;
            int c  = (t & 15) * 8;
            #pragma unroll
            for (int i = 0; i < 4; ++i) {
                int row = i * 16 + rr;
                *(int4*)&Kl[row][c] = *(const int4*)(kg + (size_t)row * DIM + c);
                bf16x8 vv = *(const bf16x8*)(vg + (size_t)row * DIM + c);
                #pragma unroll
                for (int j = 0; j < 8; ++j) {
                    int cc  = c + j;
                    int col = (((row >> 3) ^ ((cc >> 3) & 7)) << 3) | (row & 7);
                    Vt[cc][col] = vv[j];
                }
            }
        }
        __syncthreads();

        // ---- S = Q K^T ----
        f32x4 s[4];
        #pragma unroll
        for (int kc = 0; kc < 4; ++kc) {
            f32x4 acc = (f32x4){0.f, 0.f, 0.f, 0.f};
            #pragma unroll
            for (int dc = 0; dc < 4; ++dc) {
                bf16x8 kf = *(const bf16x8*)&Kl[kc * 16 + l15][dc * 32 + l4 * 8];
                acc = __builtin_amdgcn_mfma_f32_16x16x32_bf16(qf[dc], kf, acc, 0, 0, 0);
            }
            s[kc] = acc;
        }

        // ---- scale + causal mask + online softmax ----
        const bool diag = (jt == qt);
        float rowmax[4];
        #pragma unroll
        for (int r = 0; r < 4; ++r) rowmax[r] = -INFINITY;
        #pragma unroll
        for (int kc = 0; kc < 4; ++kc) {
            int key = jt * 64 + kc * 16 + l15;
            #pragma unroll
            for (int r = 0; r < 4; ++r) {
                float sv = s[kc][r] * scale;
                if (diag) {
                    int qrow = qb0 + w * 16 + l4 * 4 + r;
                    if (key > qrow) sv = -INFINITY;
                }
                s[kc][r] = sv;
                rowmax[r] = fmaxf(rowmax[r], sv);
            }
        }
        #pragma unroll
        for (int r = 0; r < 4; ++r) {
            float x2 = rowmax[r];
            x2 = fmaxf(x2, __shfl_xor(x2, 1));
            x2 = fmaxf(x2, __shfl_xor(x2, 2));
            x2 = fmaxf(x2, __shfl_xor(x2, 4));
            x2 = fmaxf(x2, __shfl_xor(x2, 8));
            rowmax[r] = x2;
        }
        float alpha[4];
        #pragma unroll
        for (int r = 0; r < 4; ++r) {
            float mnew = fmaxf(mr[r], rowmax[r]);
            alpha[r]   = __expf(mr[r] - mnew);
            mr[r]      = mnew;
        }
        float rowsum[4] = {0.f, 0.f, 0.f, 0.f};
        #pragma unroll
        for (int kc = 0; kc < 4; ++kc)
            #pragma unroll
            for (int r = 0; r < 4; ++r) {
                float p = __expf(s[kc][r] - mr[r]);
                s[kc][r] = p;
                rowsum[r] += p;
            }
        #pragma unroll
        for (int r = 0; r < 4; ++r) {
            float x2 = rowsum[r];
            x2 += __shfl_xor(x2, 1);
            x2 += __shfl_xor(x2, 2);
            x2 += __shfl_xor(x2, 4);
            x2 += __shfl_xor(x2, 8);
            lr[r] = lr[r] * alpha[r] + x2;
        }
        #pragma unroll
        for (int df = 0; df < 8; ++df)
            #pragma unroll
            for (int r = 0; r < 4; ++r) o[df][r] *= alpha[r];

        // ---- P -> bf16 A-fragment layout via per-wave LDS ----
        #pragma unroll
        for (int kc = 0; kc < 4; ++kc)
            #pragma unroll
            for (int r = 0; r < 4; ++r)
                Pl[w][l4 * 4 + r][kc * 16 + l15] = (__bf16)s[kc][r];

        // ---- O += P V ----
        #pragma unroll
        for (int pc = 0; pc < 2; ++pc) {
            bf16x8 pa = *(const bf16x8*)&Pl[w][l15][pc * 32 + l4 * 8];
            #pragma unroll
            for (int df = 0; df < 8; ++df) {
                int cc  = df * 16 + l15;
                int kch = (pc * 4 + l4) ^ ((cc >> 3) & 7);
                bf16x8 vf = *(const bf16x8*)&Vt[cc][kch * 8];
                o[df] = __builtin_amdgcn_mfma_f32_16x16x32_bf16(pa, vf, o[df], 0, 0, 0);
            }
        }
    }

    if (!SPLIT || nch == 1) {
        // final output
        float inv[4];
        #pragma unroll
        for (int r = 0; r < 4; ++r) inv[r] = 1.0f / lr[r];
        float* op = out + base;
        #pragma unroll
        for (int df = 0; df < 8; ++df)
            #pragma unroll
            for (int r = 0; r < 4; ++r) {
                int row = qb0 + w * 16 + l4 * 4 + r;
                op[(size_t)row * DIM + df * 16 + l15] = o[df][r] * inv[r];
            }
    } else {
        // partial (m, l, unnormalized O) to workspace
        float* sp = part + (size_t)slot * SLOT_F32;
        #pragma unroll
        for (int r = 0; r < 4; ++r) {
            int rl = w * 16 + l4 * 4 + r;
            if (l15 == 0) { sp[rl] = mr[r]; sp[64 + rl] = lr[r]; }
        }
        #pragma unroll
        for (int df = 0; df < 8; ++df)
            #pragma unroll
            for (int r = 0; r < 4; ++r) {
                int rl = w * 16 + l4 * 4 + r;
                sp[128 + (size_t)rl * 128 + df * 16 + l15] = o[df][r];
            }
    }
}

// ---------------------------------------------------------------------------
// Kernel 3: combine partials for qt >= 8. Grid (56, B), 256 threads.
// Thread t: row = t>>2, cols [(t&3)*32, +32).
// ---------------------------------------------------------------------------
__global__ __launch_bounds__(256) void combine(
    const float* __restrict__ part, float* __restrict__ out)
{
    const int qt  = blockIdx.x + 8;
    const int b   = blockIdx.y;
    const int g   = qt >> 3;
    const int nch = g + 1;
    const int slot0 = b * TASKS_PER_B + 4 * g * (g + 1) + (qt & 7) * nch;

    const int t   = threadIdx.x;
    const int row = t >> 2;
    const int c0  = (t & 3) * 32;

    float M = -INFINITY;
    for (int c = 0; c < nch; ++c)
        M = fmaxf(M, part[(size_t)(slot0 + c) * SLOT_F32 + row]);
    float L = 0.f;
    for (int c = 0; c < nch; ++c) {
        const float* sp = part + (size_t)(slot0 + c) * SLOT_F32;
        L += sp[64 + row] * __expf(sp[row] - M);
    }

    float4 acc[8];
    #pragma unroll
    for (int i = 0; i < 8; ++i) acc[i] = (float4){0.f, 0.f, 0.f, 0.f};
    for (int c = 0; c < nch; ++c) {
        const float* sp = part + (size_t)(slot0 + c) * SLOT_F32;
        float wgt = __expf(sp[row] - M);
        const float* op = sp + 128 + (size_t)row * 128 + c0;
        #pragma unroll
        for (int i = 0; i < 8; ++i) {
            float4 f = *(const float4*)(op + i * 4);
            acc[i].x += wgt * f.x; acc[i].y += wgt * f.y;
            acc[i].z += wgt * f.z; acc[i].w += wgt * f.w;
        }
    }
    float invL = 1.0f / L;
    float* o = out + ((size_t)b * SEQ + (size_t)qt * 64 + row) * DIM + c0;
    #pragma unroll
    for (int i = 0; i < 8; ++i) {
        float4 f;
        f.x = acc[i].x * invL; f.y = acc[i].y * invL;
        f.z = acc[i].z * invL; f.w = acc[i].w * invL;
        *(float4*)(o + i * 4) = f;
    }
}

// ---------------------------------------------------------------------------
extern "C" void kernel_launch(void* const* d_in, const int* in_sizes, int n_in,
                              void* d_out, int out_size, void* d_ws, size_t ws_size,
                              hipStream_t stream) {
    const float* x  = (const float*)d_in[0];
    const float* Wq = (const float*)d_in[1];
    const float* Wk = (const float*)d_in[2];
    const float* Wv = (const float*)d_in[3];
    float* out = (float*)d_out;

    __bf16* qw = (__bf16*)d_ws;
    __bf16* kw = qw + (size_t)BATCH * SEQ * DIM;
    __bf16* vw = kw + (size_t)BATCH * SEQ * DIM;
    float*  part = (float*)((char*)d_ws + QKV_BYTES);

    qkv_proj<<<dim3(BATCH * SEQ / 128, 3), 256, 0, stream>>>(x, Wq, Wk, Wv, qw, kw, vw);

    if (ws_size >= QKV_BYTES + PART_BYTES) {
        attn<true><<<dim3(TASKS_PER_B, BATCH), 256, 0, stream>>>(qw, kw, vw, out, part);
        combine<<<dim3(56, BATCH), 256, 0, stream>>>(part, out);
    } else {
        attn<false><<<dim3(SEQ / 64, BATCH), 256, 0, stream>>>(qw, kw, vw, out, part);
    }
}